// Round 10
// baseline (43.534 us; speedup 1.0000x reference)
//
#include <hip/hip_runtime.h>
#include <hip/hip_bf16.h>
#include <math.h>

typedef __attribute__((ext_vector_type(8))) short short8;
typedef __attribute__((ext_vector_type(4))) float f32x4;
typedef __attribute__((ext_vector_type(16))) float f32x16;
typedef unsigned int u32;
typedef unsigned long long u64;

// fast round-to-nearest-even f32 -> bf16 (finite values)
__device__ __forceinline__ ushort f2bf(float f) {
    u32 u = __float_as_uint(f);
    return (ushort)((u + 0x7fffu + ((u >> 16) & 1u)) >> 16);
}
__device__ __forceinline__ float bf2f(ushort h) {
    return __uint_as_float(((u32)h) << 16);
}

// ---------------------------------------------------------------------------
// Weight pack: lw (32,144,3,3) f32 -> bf16 A-fragments, K-SPLIT in 2 halves.
// Page = kk*45 + tap*5 + ks  (90 pages x 64 lanes x 8 bf16).
// Per-half K=80: k<64 -> spline ch kk*64+k; 64..71 -> gelu ch 128+kk*8+(k-64);
// 72..79 zero pad. A-frag: row(oc)=lane&31, k = ks*16 + (lane>>5)*8 + e.
// ---------------------------------------------------------------------------
__global__ void wtrans(const float* __restrict__ lw, ushort* __restrict__ w2) {
    int t = blockIdx.x * 256 + threadIdx.x;
    if (t >= 5760) return;
    int l    = t & 63;
    int page = t >> 6;              // 0..89
    int ks  = page % 5;
    int tap = (page / 5) % 9;
    int kk  = page / 45;
    int oc = l & 31;
    int kbase = ks * 16 + ((l >> 5) << 3);
    short8 v;
#pragma unroll
    for (int e = 0; e < 8; ++e) {
        int k = kbase + e;          // 0..79
        float val = 0.f;
        if (k < 64)       val = lw[(oc * 144 + kk * 64 + k) * 9 + tap];
        else if (k < 72)  val = lw[(oc * 144 + 128 + kk * 8 + (k - 64)) * 9 + tap];
        v[e] = (short)f2bf(val);
    }
    ((short8*)w2)[t] = v;
}

// ---------------------------------------------------------------------------
// MFMA implicit-GEMM KAN conv, 32x32x16 bf16, K-split: block = (b,g,kk,tile),
// 8 input channels, K=80. Block = 128 threads = 2 INDEPENDENT waves, each
// owning one 32-pixel subtile for all 9 taps (no combine, one barrier).
// Halo 6x18=108 px, row stride 88 ushort (176B = 11x16B, odd -> no conflict).
// LDS 19.0 KB -> 8 blocks/CU. Partial bf16 y to ws (summed in instnorm).
// ---------------------------------------------------------------------------
__global__ __launch_bounds__(128, 4) void kanconv(const float* __restrict__ x,
                                                  const ushort* __restrict__ w2,
                                                  ushort* __restrict__ yraw) {
    __shared__ __align__(16) ushort Fs[108 * 88];    // 19,008 B
    const int tid  = threadIdx.x;
    const int tile = blockIdx.x;          // 0..63 : 16 row-tiles x 4 col-tiles
    const int b    = blockIdx.y;
    const int gz   = blockIdx.z;          // 0..7
    const int g    = gz & 3;
    const int kk   = gz >> 2;
    const int h0 = (tile >> 2) * 4;
    const int w0 = (tile & 3) * 16;
    const float* xg = x + ((size_t)(b * 64 + g * 16 + kk * 8)) * 4096;

    // ---- phase 1: prefetch 7 x values (independent loads) ----
    float xv[7];
    unsigned imgbits = 0;
#pragma unroll
    for (int it = 0; it < 7; ++it) {
        int e = it * 128 + tid;           // 0..895, need < 864
        float v = 0.f;
        if (e < 864) {
            int icg = e / 108;            // 0..7 local channel
            int p   = e - icg * 108;
            int py = p / 18, px = p - py * 18;
            int hy = h0 + py - 1, wx = w0 + px - 1;
            if (((unsigned)hy < 64u) && ((unsigned)wx < 64u)) {
                v = xg[icg * 4096 + hy * 64 + wx];
                imgbits |= (1u << it);
            }
        }
        xv[it] = v;
    }

    // ---- phase 2: feature math + LDS writes ----
#pragma unroll
    for (int it = 0; it < 7; ++it) {
        int e = it * 128 + tid;
        if (e < 864) {
            int icg = e / 108;
            int p   = e - icg * 108;
            bool img = (imgbits >> it) & 1u;
            float v = xv[it];
            // uniform cubic B-spline closed form; knots -2.2 + 0.4*i
            float tpos = (v + 2.2f) * 2.5f;
            float cf = floorf(tpos);
            int ci = (int)cf;
            float u = tpos - cf;
            float u2 = u * u, u3 = u2 * u, om = 1.f - u;
            const float s6 = 1.f / 6.f;
            float q0 = om * om * om * s6;
            float q1 = (4.f - 6.f * u2 + 3.f * u3) * s6;
            float q2 = (1.f + 3.f * u + 3.f * u2 - 3.f * u3) * s6;
            float q3 = u3 * s6;
            u64 Q =   (u64)f2bf(q0)
                    | ((u64)f2bf(q1) << 16)
                    | ((u64)f2bf(q2) << 32)
                    | ((u64)f2bf(q3) << 48);
            u64 lo = 0, hi = 0;
            if (img && ci >= 0 && ci <= 10) {
                int s = ci * 16 - 48;
                if (s < 0)        { lo = Q >> (-s); }
                else if (s < 64)  { lo = Q << s; hi = s ? (Q >> (64 - s)) : 0ull; }
                else              { hi = Q << (s - 64); }
            }
            union { u64 u64v[2]; short8 s8; } un;
            un.u64v[0] = lo; un.u64v[1] = hi;
            ushort* row = &Fs[p * 88];
            *(short8*)(row + icg * 8) = un.s8;
            // gelu via branch-free poly erf (A&S 7.1.26); v==0 -> ge==0
            float z  = v * 0.70710678118654752f;
            float az = fabsf(z);
            float tt = 1.f / fmaf(0.3275911f, az, 1.f);
            float poly = tt * fmaf(tt, fmaf(tt, fmaf(tt, fmaf(tt, 1.061405429f,
                          -1.453152027f), 1.421413741f), -0.284496736f),
                          0.254829592f);
            float er = 1.f - poly * __expf(-z * z);
            er = (z < 0.f) ? -er : er;
            float ge = 0.5f * v * (1.f + er);
            row[64 + icg] = f2bf(ge);
        }
    }
    // zero pad k in [72,80)
    {
        short8 z8 = {0, 0, 0, 0, 0, 0, 0, 0};
        if (tid < 108) *(short8*)&Fs[tid * 88 + 72] = z8;
    }
    __syncthreads();

    const int wv = tid >> 6;              // 0..1 : pixel subtile
    const int l  = tid & 63;
    const int la = l & 31, klo = l >> 5;
    const int pix = wv * 32 + la;
    const int prow = pix >> 4, pcol = pix & 15;

    f32x16 acc;
#pragma unroll
    for (int i = 0; i < 16; ++i) acc[i] = 0.f;
    const short8* w8 = (const short8*)w2 + kk * 45 * 64;

#pragma unroll
    for (int tap = 0; tap < 9; ++tap) {
        const int kh = tap / 3, kw = tap - kh * 3;
        const ushort* fb = &Fs[((prow + kh) * 18 + (pcol + kw)) * 88 + klo * 8];
        const short8* ap = w8 + tap * 5 * 64 + l;
#pragma unroll
        for (int ks = 0; ks < 5; ++ks) {
            short8 a  = ap[ks * 64];                      // weights (A)
            short8 bf = *(const short8*)(fb + ks * 16);   // features (B)
            acc = __builtin_amdgcn_mfma_f32_32x32x16_bf16(a, bf, acc, 0, 0, 0);
        }
    }

    // D: col(pixel) = lane&31, row(oc) = (r&3) + 8*(r>>2) + 4*klo
    ushort* yb = yraw + (size_t)kk * 4194304
               + (((size_t)b * 128 + g * 32) * 64 + h0 + prow) * 64 + w0 + pcol;
#pragma unroll
    for (int r = 0; r < 16; ++r) {
        int oc = (r & 3) + 8 * (r >> 2) + 4 * klo;
        yb[(size_t)oc * 4096] = f2bf(acc[r]);
    }
}

// ---------------------------------------------------------------------------
// Instance-norm + PReLU: sum the two bf16 K-partials, normalize, write f32.
// One block per (b,c); 16 contiguous values per thread.
// ---------------------------------------------------------------------------
__global__ __launch_bounds__(256) void instnorm(const ushort* __restrict__ yraw,
                                                float* __restrict__ y,
                                                const float* __restrict__ prelu) {
    const int blk = blockIdx.x;  // b*128 + c
    const int tid = threadIdx.x;
    const short8* rp0 = (const short8*)(yraw + (size_t)blk * 4096);
    const short8* rp1 = (const short8*)(yraw + 4194304 + (size_t)blk * 4096);
    short8 a0 = rp0[tid * 2], a1 = rp0[tid * 2 + 1];
    short8 c0 = rp1[tid * 2], c1 = rp1[tid * 2 + 1];
    float v[16];
#pragma unroll
    for (int j = 0; j < 8; ++j) {
        v[j]     = bf2f((ushort)a0[j]) + bf2f((ushort)c0[j]);
        v[8 + j] = bf2f((ushort)a1[j]) + bf2f((ushort)c1[j]);
    }
    float s = 0.f, s2 = 0.f;
#pragma unroll
    for (int j = 0; j < 16; ++j) { s += v[j]; s2 += v[j] * v[j]; }
#pragma unroll
    for (int off = 32; off > 0; off >>= 1) {
        s  += __shfl_down(s, off);
        s2 += __shfl_down(s2, off);
    }
    __shared__ float red[8];
    int wave = tid >> 6;
    if ((tid & 63) == 0) { red[wave] = s; red[4 + wave] = s2; }
    __syncthreads();
    float S  = red[0] + red[1] + red[2] + red[3];
    float S2 = red[4] + red[5] + red[6] + red[7];
    float mean = S * (1.0f / 4096.0f);
    float var  = S2 * (1.0f / 4096.0f) - mean * mean;
    float rstd = rsqrtf(var + 1e-5f);
    float slope = prelu[(blk >> 5) & 3];
    float4* op = (float4*)(y + (size_t)blk * 4096) + tid * 4;
#pragma unroll
    for (int k = 0; k < 4; ++k) {
        float4 o;
        float t;
        t = (v[k * 4 + 0] - mean) * rstd; o.x = t >= 0.f ? t : slope * t;
        t = (v[k * 4 + 1] - mean) * rstd; o.y = t >= 0.f ? t : slope * t;
        t = (v[k * 4 + 2] - mean) * rstd; o.z = t >= 0.f ? t : slope * t;
        t = (v[k * 4 + 3] - mean) * rstd; o.w = t >= 0.f ? t : slope * t;
        op[k] = o;
    }
}

extern "C" void kernel_launch(void* const* d_in, const int* in_sizes, int n_in,
                              void* d_out, int out_size, void* d_ws, size_t ws_size,
                              hipStream_t stream) {
    const float* x     = (const float*)d_in[0];
    const float* lw    = (const float*)d_in[1];
    const float* prelu = (const float*)d_in[2];
    float*  out  = (float*)d_out;
    ushort* w2   = (ushort*)d_ws;                       // 90*64*16 = 92,160 B
    ushort* yraw = (ushort*)((char*)d_ws + 92160);      // 2 x 8 MB bf16 partials

    wtrans<<<23, 256, 0, stream>>>(lw, w2);
    dim3 grid(64, 8, 8);
    kanconv<<<grid, 128, 0, stream>>>(x, w2, yraw);
    instnorm<<<1024, 256, 0, stream>>>(yraw, out, prelu);
}

// Round 11
// 40.222 us; speedup vs baseline: 1.0823x; 1.0823x over previous
//
#include <hip/hip_runtime.h>
#include <hip/hip_bf16.h>
#include <math.h>

typedef __attribute__((ext_vector_type(8))) short short8;
typedef __attribute__((ext_vector_type(4))) float f32x4;
typedef __attribute__((ext_vector_type(16))) float f32x16;
typedef unsigned int u32;
typedef unsigned long long u64;

// fast round-to-nearest-even f32 -> bf16 (finite values)
__device__ __forceinline__ ushort f2bf(float f) {
    u32 u = __float_as_uint(f);
    return (ushort)((u + 0x7fffu + ((u >> 16) & 1u)) >> 16);
}
__device__ __forceinline__ float bf2f(ushort h) {
    return __uint_as_float(((u32)h) << 16);
}

// ---------------------------------------------------------------------------
// Weight pack: layer_weight (32,144,3,3) f32 -> bf16 A-fragments for
// mfma_f32_32x32x16_bf16 (weights = A operand, M=32=oc, K=144).
// Page = tap*9 + ks. A-frag: row(oc) = lane&31, k = ks*16 + (lane>>5)*8 + e.
// ---------------------------------------------------------------------------
__global__ void wtrans(const float* __restrict__ lw, ushort* __restrict__ w2) {
    int t = blockIdx.x * 256 + threadIdx.x;
    if (t >= 5184) return;
    int l    = t & 63;
    int page = t >> 6;          // 0..80
    int ks  = page % 9;
    int tap = page / 9;
    int oc = l & 31;
    int kbase = ks * 16 + ((l >> 5) << 3);
    short8 v;
#pragma unroll
    for (int e = 0; e < 8; ++e) {
        int k = kbase + e;      // < 144 always
        v[e] = (short)f2bf(lw[(oc * 144 + k) * 9 + tap]);
    }
    ((short8*)w2)[t] = v;
}

// ---------------------------------------------------------------------------
// MFMA implicit-GEMM KAN conv, 32x32x16 bf16, K=144. Raw bf16 y out.
// Block = (b, g, 4x16 tile), halo 6x18, row stride 152 ushort (19x16B, odd).
// Waves own taps {0,1},{2,3},{4,5},{6,7,8}; each computes both pixel tiles.
// Weight fragments PRELOADED into registers: tapA loads overlap staging,
// tapB loads overlap tapA's MFMAs (no serial L2 latency in the inner loop).
// 6-slot stride-20 combine scratch (conflict-free).
// ---------------------------------------------------------------------------
__global__ __launch_bounds__(256, 4) void kanconv(const float* __restrict__ x,
                                                  const ushort* __restrict__ w2,
                                                  ushort* __restrict__ yraw) {
    __shared__ __align__(16) ushort Fs[108 * 152];   // 32,832 B
    const int tid  = threadIdx.x;
    const int tile = blockIdx.x;          // 0..63 : 16 row-tiles x 4 col-tiles
    const int b    = blockIdx.y;
    const int g    = blockIdx.z;
    const int h0 = (tile >> 2) * 4;
    const int w0 = (tile & 3) * 16;
    const float* xg = x + ((size_t)(b * 64 + g * 16)) * 4096;

    const int wv = tid >> 6;
    const int l  = tid & 63;

    // ---- phase 1: prefetch the 7 x values (independent loads) ----
    float xv[7];
    unsigned imgbits = 0;
#pragma unroll
    for (int it = 0; it < 7; ++it) {
        int e = it * 256 + tid;
        float v = 0.f;
        if (e < 1728) {
            int icg = e / 108;
            int p   = e - icg * 108;
            int py = p / 18, px = p - py * 18;
            int hy = h0 + py - 1, wx = w0 + px - 1;
            if (((unsigned)hy < 64u) && ((unsigned)wx < 64u)) {
                v = xg[icg * 4096 + hy * 64 + wx];
                imgbits |= (1u << it);
            }
        }
        xv[it] = v;
    }

    // ---- issue tap-A weight loads NOW: they complete during staging ----
    const short8* w8  = (const short8*)w2;
    const short8* ap0 = w8 + (wv * 2 + 0) * 576 + l;
    const short8* ap1 = w8 + (wv * 2 + 1) * 576 + l;
    short8 wA0 = ap0[0 * 64], wA1 = ap0[1 * 64], wA2 = ap0[2 * 64];
    short8 wA3 = ap0[3 * 64], wA4 = ap0[4 * 64], wA5 = ap0[5 * 64];
    short8 wA6 = ap0[6 * 64], wA7 = ap0[7 * 64], wA8 = ap0[8 * 64];

    // ---- phase 2: feature math + LDS writes ----
#pragma unroll
    for (int it = 0; it < 7; ++it) {
        int e = it * 256 + tid;
        if (e < 1728) {
            int icg = e / 108;
            int p   = e - icg * 108;
            bool img = (imgbits >> it) & 1u;
            float v = xv[it];
            // uniform cubic B-spline closed form; knots -2.2 + 0.4*i
            float tpos = (v + 2.2f) * 2.5f;
            float cf = floorf(tpos);
            int ci = (int)cf;
            float u = tpos - cf;
            float u2 = u * u, u3 = u2 * u, om = 1.f - u;
            const float s6 = 1.f / 6.f;
            float q0 = om * om * om * s6;
            float q1 = (4.f - 6.f * u2 + 3.f * u3) * s6;
            float q2 = (1.f + 3.f * u + 3.f * u2 - 3.f * u3) * s6;
            float q3 = u3 * s6;
            u64 Q =   (u64)f2bf(q0)
                    | ((u64)f2bf(q1) << 16)
                    | ((u64)f2bf(q2) << 32)
                    | ((u64)f2bf(q3) << 48);
            u64 lo = 0, hi = 0;
            if (img && ci >= 0 && ci <= 10) {
                int s = ci * 16 - 48;
                if (s < 0)        { lo = Q >> (-s); }
                else if (s < 64)  { lo = Q << s; hi = s ? (Q >> (64 - s)) : 0ull; }
                else              { hi = Q << (s - 64); }
            }
            union { u64 u64v[2]; short8 s8; } un;
            un.u64v[0] = lo; un.u64v[1] = hi;
            ushort* row = &Fs[p * 152];
            *(short8*)(row + icg * 8) = un.s8;
            // gelu via branch-free poly erf (A&S 7.1.26); v==0 -> ge==0
            float z  = v * 0.70710678118654752f;
            float az = fabsf(z);
            float tt = 1.f / fmaf(0.3275911f, az, 1.f);
            float poly = tt * fmaf(tt, fmaf(tt, fmaf(tt, fmaf(tt, 1.061405429f,
                          -1.453152027f), 1.421413741f), -0.284496736f),
                          0.254829592f);
            float er = 1.f - poly * __expf(-z * z);
            er = (z < 0.f) ? -er : er;
            float ge = 0.5f * v * (1.f + er);
            row[128 + icg] = f2bf(ge);
        }
    }
    __syncthreads();

    // ---- issue tap-B weight loads: in flight under tap-A's MFMAs ----
    short8 wB0 = ap1[0 * 64], wB1 = ap1[1 * 64], wB2 = ap1[2 * 64];
    short8 wB3 = ap1[3 * 64], wB4 = ap1[4 * 64], wB5 = ap1[5 * 64];
    short8 wB6 = ap1[6 * 64], wB7 = ap1[7 * 64], wB8 = ap1[8 * 64];

    const int la = l & 31, klo = l >> 5;
    const int p0row = la >> 4, p0col = la & 15;   // tile0: rows 0-1; tile1: +2

    f32x16 accA, accB;
#pragma unroll
    for (int i = 0; i < 16; ++i) { accA[i] = 0.f; accB[i] = 0.f; }

#define TAP_MFMA(TAP, W0, W1, W2, W3, W4, W5, W6, W7, W8)                      \
    do {                                                                       \
        const int kh_ = (TAP) / 3, kw_ = (TAP) - kh_ * 3;                      \
        const ushort* fb0_ =                                                   \
            &Fs[((p0row + kh_) * 18 + (p0col + kw_)) * 152 + klo * 8];         \
        const ushort* fb1_ = fb0_ + 2 * 18 * 152;                              \
        short8 b0_, b1_;                                                       \
        b0_ = *(const short8*)(fb0_ + 0 * 16);                                 \
        b1_ = *(const short8*)(fb1_ + 0 * 16);                                 \
        accA = __builtin_amdgcn_mfma_f32_32x32x16_bf16(W0, b0_, accA, 0, 0, 0);\
        accB = __builtin_amdgcn_mfma_f32_32x32x16_bf16(W0, b1_, accB, 0, 0, 0);\
        b0_ = *(const short8*)(fb0_ + 1 * 16);                                 \
        b1_ = *(const short8*)(fb1_ + 1 * 16);                                 \
        accA = __builtin_amdgcn_mfma_f32_32x32x16_bf16(W1, b0_, accA, 0, 0, 0);\
        accB = __builtin_amdgcn_mfma_f32_32x32x16_bf16(W1, b1_, accB, 0, 0, 0);\
        b0_ = *(const short8*)(fb0_ + 2 * 16);                                 \
        b1_ = *(const short8*)(fb1_ + 2 * 16);                                 \
        accA = __builtin_amdgcn_mfma_f32_32x32x16_bf16(W2, b0_, accA, 0, 0, 0);\
        accB = __builtin_amdgcn_mfma_f32_32x32x16_bf16(W2, b1_, accB, 0, 0, 0);\
        b0_ = *(const short8*)(fb0_ + 3 * 16);                                 \
        b1_ = *(const short8*)(fb1_ + 3 * 16);                                 \
        accA = __builtin_amdgcn_mfma_f32_32x32x16_bf16(W3, b0_, accA, 0, 0, 0);\
        accB = __builtin_amdgcn_mfma_f32_32x32x16_bf16(W3, b1_, accB, 0, 0, 0);\
        b0_ = *(const short8*)(fb0_ + 4 * 16);                                 \
        b1_ = *(const short8*)(fb1_ + 4 * 16);                                 \
        accA = __builtin_amdgcn_mfma_f32_32x32x16_bf16(W4, b0_, accA, 0, 0, 0);\
        accB = __builtin_amdgcn_mfma_f32_32x32x16_bf16(W4, b1_, accB, 0, 0, 0);\
        b0_ = *(const short8*)(fb0_ + 5 * 16);                                 \
        b1_ = *(const short8*)(fb1_ + 5 * 16);                                 \
        accA = __builtin_amdgcn_mfma_f32_32x32x16_bf16(W5, b0_, accA, 0, 0, 0);\
        accB = __builtin_amdgcn_mfma_f32_32x32x16_bf16(W5, b1_, accB, 0, 0, 0);\
        b0_ = *(const short8*)(fb0_ + 6 * 16);                                 \
        b1_ = *(const short8*)(fb1_ + 6 * 16);                                 \
        accA = __builtin_amdgcn_mfma_f32_32x32x16_bf16(W6, b0_, accA, 0, 0, 0);\
        accB = __builtin_amdgcn_mfma_f32_32x32x16_bf16(W6, b1_, accB, 0, 0, 0);\
        b0_ = *(const short8*)(fb0_ + 7 * 16);                                 \
        b1_ = *(const short8*)(fb1_ + 7 * 16);                                 \
        accA = __builtin_amdgcn_mfma_f32_32x32x16_bf16(W7, b0_, accA, 0, 0, 0);\
        accB = __builtin_amdgcn_mfma_f32_32x32x16_bf16(W7, b1_, accB, 0, 0, 0);\
        b0_ = *(const short8*)(fb0_ + 8 * 16);                                 \
        b1_ = *(const short8*)(fb1_ + 8 * 16);                                 \
        accA = __builtin_amdgcn_mfma_f32_32x32x16_bf16(W8, b0_, accA, 0, 0, 0);\
        accB = __builtin_amdgcn_mfma_f32_32x32x16_bf16(W8, b1_, accB, 0, 0, 0);\
    } while (0)

    // tap A (weights already resident)
    TAP_MFMA(wv * 2 + 0, wA0, wA1, wA2, wA3, wA4, wA5, wA6, wA7, wA8);
    // tap B
    TAP_MFMA(wv * 2 + 1, wB0, wB1, wB2, wB3, wB4, wB5, wB6, wB7, wB8);
    // wave 3: 9th tap (kh=2,kw=2), loads issued after tapA, hidden under tapB
    if (wv == 3) {
        const short8* ap2 = w8 + 8 * 576 + l;
        short8 wC0 = ap2[0 * 64], wC1 = ap2[1 * 64], wC2 = ap2[2 * 64];
        short8 wC3 = ap2[3 * 64], wC4 = ap2[4 * 64], wC5 = ap2[5 * 64];
        short8 wC6 = ap2[6 * 64], wC7 = ap2[7 * 64], wC8 = ap2[8 * 64];
        TAP_MFMA(8, wC0, wC1, wC2, wC3, wC4, wC5, wC6, wC7, wC8);
    }
#undef TAP_MFMA

    // ---- combine: 6 slots [slot][lane] stride 20 f32 (30,720 B in Fs) ----
    __syncthreads();                      // all feature reads done
    float* comb = (float*)Fs;
    if (wv != 0) {                        // tile0 partials: waves 1,2,3 -> 0,1,2
        float* cp = comb + ((wv - 1) * 64 + l) * 20;
        *(f32x4*)(cp + 0)  = f32x4{accA[0], accA[1], accA[2], accA[3]};
        *(f32x4*)(cp + 4)  = f32x4{accA[4], accA[5], accA[6], accA[7]};
        *(f32x4*)(cp + 8)  = f32x4{accA[8], accA[9], accA[10], accA[11]};
        *(f32x4*)(cp + 12) = f32x4{accA[12], accA[13], accA[14], accA[15]};
    }
    if (wv != 1) {                        // tile1 partials: waves 0,2,3 -> 3,4,5
        int slot = (wv == 0) ? 3 : (2 + wv);
        float* cp = comb + (slot * 64 + l) * 20;
        *(f32x4*)(cp + 0)  = f32x4{accB[0], accB[1], accB[2], accB[3]};
        *(f32x4*)(cp + 4)  = f32x4{accB[4], accB[5], accB[6], accB[7]};
        *(f32x4*)(cp + 8)  = f32x4{accB[8], accB[9], accB[10], accB[11]};
        *(f32x4*)(cp + 12) = f32x4{accB[12], accB[13], accB[14], accB[15]};
    }
    __syncthreads();
    if (wv < 2) {
        f32x16 sum = (wv == 0) ? accA : accB;
        const int sbase = (wv == 0) ? 0 : 3;
#pragma unroll
        for (int s = 0; s < 3; ++s) {
            const float* cp = comb + ((sbase + s) * 64 + l) * 20;
            f32x4 c0 = *(const f32x4*)(cp + 0);
            f32x4 c1 = *(const f32x4*)(cp + 4);
            f32x4 c2 = *(const f32x4*)(cp + 8);
            f32x4 c3 = *(const f32x4*)(cp + 12);
#pragma unroll
            for (int r = 0; r < 4; ++r) {
                sum[r]      += c0[r];
                sum[r + 4]  += c1[r];
                sum[r + 8]  += c2[r];
                sum[r + 12] += c3[r];
            }
        }
        // D: col(pixel) = lane&31, row(oc) = (r&3) + 8*(r>>2) + 4*klo
        const int pix = wv * 32 + la;
        const int prow = pix >> 4, pcol = pix & 15;
        ushort* yb = yraw + (((size_t)b * 128 + g * 32) * 64 + h0 + prow) * 64
                          + w0 + pcol;
#pragma unroll
        for (int r = 0; r < 16; ++r) {
            int oc = (r & 3) + 8 * (r >> 2) + 4 * klo;
            yb[(size_t)oc * 4096] = f2bf(sum[r]);
        }
    }
}

// ---------------------------------------------------------------------------
// Instance-norm + PReLU from bf16 raw y: one block per (b,c); each thread owns
// 16 CONTIGUOUS values; 2 b128 loads + 4 float4 stores per thread.
// ---------------------------------------------------------------------------
__global__ __launch_bounds__(256) void instnorm(const ushort* __restrict__ yraw,
                                                float* __restrict__ y,
                                                const float* __restrict__ prelu) {
    const int blk = blockIdx.x;  // b*128 + c
    const int tid = threadIdx.x;
    const short8* rp = (const short8*)(yraw + (size_t)blk * 4096);
    short8 a = rp[tid * 2], c = rp[tid * 2 + 1];
    float v[16];
#pragma unroll
    for (int j = 0; j < 8; ++j) {
        v[j]     = bf2f((ushort)a[j]);
        v[8 + j] = bf2f((ushort)c[j]);
    }
    float s = 0.f, s2 = 0.f;
#pragma unroll
    for (int j = 0; j < 16; ++j) { s += v[j]; s2 += v[j] * v[j]; }
#pragma unroll
    for (int off = 32; off > 0; off >>= 1) {
        s  += __shfl_down(s, off);
        s2 += __shfl_down(s2, off);
    }
    __shared__ float red[8];
    int wave = tid >> 6;
    if ((tid & 63) == 0) { red[wave] = s; red[4 + wave] = s2; }
    __syncthreads();
    float S  = red[0] + red[1] + red[2] + red[3];
    float S2 = red[4] + red[5] + red[6] + red[7];
    float mean = S * (1.0f / 4096.0f);
    float var  = S2 * (1.0f / 4096.0f) - mean * mean;
    float rstd = rsqrtf(var + 1e-5f);
    float slope = prelu[(blk >> 5) & 3];
    float4* op = (float4*)(y + (size_t)blk * 4096) + tid * 4;
#pragma unroll
    for (int k = 0; k < 4; ++k) {
        float4 o;
        float t;
        t = (v[k * 4 + 0] - mean) * rstd; o.x = t >= 0.f ? t : slope * t;
        t = (v[k * 4 + 1] - mean) * rstd; o.y = t >= 0.f ? t : slope * t;
        t = (v[k * 4 + 2] - mean) * rstd; o.z = t >= 0.f ? t : slope * t;
        t = (v[k * 4 + 3] - mean) * rstd; o.w = t >= 0.f ? t : slope * t;
        op[k] = o;
    }
}

extern "C" void kernel_launch(void* const* d_in, const int* in_sizes, int n_in,
                              void* d_out, int out_size, void* d_ws, size_t ws_size,
                              hipStream_t stream) {
    const float* x     = (const float*)d_in[0];
    const float* lw    = (const float*)d_in[1];
    const float* prelu = (const float*)d_in[2];
    float*  out  = (float*)d_out;
    ushort* w2   = (ushort*)d_ws;                       // 82,944 B
    ushort* yraw = (ushort*)((char*)d_ws + 92160);      // 8 MB bf16 raw y

    wtrans<<<21, 256, 0, stream>>>(lw, w2);
    dim3 grid(64, 8, 4);
    kanconv<<<grid, 256, 0, stream>>>(x, w2, yraw);
    instnorm<<<1024, 256, 0, stream>>>(yraw, out, prelu);
}

// Round 12
// 39.870 us; speedup vs baseline: 1.0919x; 1.0088x over previous
//
#include <hip/hip_runtime.h>
#include <hip/hip_bf16.h>
#include <math.h>

typedef __attribute__((ext_vector_type(8))) short short8;
typedef __attribute__((ext_vector_type(4))) float f32x4;
typedef __attribute__((ext_vector_type(16))) float f32x16;
typedef unsigned int u32;
typedef unsigned long long u64;

// fast round-to-nearest-even f32 -> bf16 (finite values)
__device__ __forceinline__ ushort f2bf(float f) {
    u32 u = __float_as_uint(f);
    return (ushort)((u + 0x7fffu + ((u >> 16) & 1u)) >> 16);
}
__device__ __forceinline__ float bf2f(ushort h) {
    return __uint_as_float(((u32)h) << 16);
}
// pack two f32 -> one u32 of 2 bf16 (RNE), single HW instr on gfx950
__device__ __forceinline__ u32 cvtpk_bf16(float a, float b) {
    u32 r;
    asm("v_cvt_pk_bf16_f32 %0, %1, %2" : "=v"(r) : "v"(a), "v"(b));
    return r;
}

// ---------------------------------------------------------------------------
// Weight pack: layer_weight (32,144,3,3) f32 -> bf16 A-fragments for
// mfma_f32_32x32x16_bf16 (weights = A operand, M=32=oc, K=144).
// Page = tap*9 + ks. A-frag: row(oc) = lane&31, k = ks*16 + (lane>>5)*8 + e.
// k-order: k<128 -> spline (icg*8+jj), 128..143 -> gelu(icg).
// ---------------------------------------------------------------------------
__global__ void wtrans(const float* __restrict__ lw, ushort* __restrict__ w2) {
    int t = blockIdx.x * 256 + threadIdx.x;
    if (t >= 5184) return;
    int l    = t & 63;
    int page = t >> 6;          // 0..80
    int ks  = page % 9;
    int tap = page / 9;
    int oc = l & 31;
    int kbase = ks * 16 + ((l >> 5) << 3);
    short8 v;
#pragma unroll
    for (int e = 0; e < 8; ++e) {
        int k = kbase + e;      // < 144 always
        v[e] = (short)f2bf(lw[(oc * 144 + k) * 9 + tap]);
    }
    ((short8*)w2)[t] = v;
}

// ---------------------------------------------------------------------------
// MFMA implicit-GEMM KAN conv, 32x32x16 bf16, K=144. Raw bf16 y out.
// Block = (b, g, 4x16 tile), halo 6x18 = 108 px, row stride 152 ushort.
// Staging split in two icg-halves (k-order makes K-slices = icg-slices):
//   stage icg0-7 | barrier | stage icg8-15 INTERLEAVED with MFMA ks0-3
//   | barrier | MFMA ks4-8.  Branch-free staging via dump row 108.
// Waves own taps {0,1},{2,3},{4,5},{6,7,8}; 6-slot stride-20 combine.
// ---------------------------------------------------------------------------
__global__ __launch_bounds__(256, 4) void kanconv(const float* __restrict__ x,
                                                  const ushort* __restrict__ w2,
                                                  ushort* __restrict__ yraw) {
    __shared__ __align__(16) ushort Fs[109 * 152];   // row 108 = dump row
    const int tid  = threadIdx.x;
    const int tile = blockIdx.x;          // 0..63 : 16 row-tiles x 4 col-tiles
    const int b    = blockIdx.y;
    const int g    = blockIdx.z;
    const int h0 = (tile >> 2) * 4;
    const int w0 = (tile & 3) * 16;
    const float* xg = x + ((size_t)(b * 64 + g * 16)) * 4096;

    // ---- prefetch all 8 x loads (two icg-halves share coords/mask) ----
    float xv1[4], xv2[4];
    unsigned imgbits = 0;
#pragma unroll
    for (int it = 0; it < 4; ++it) {
        int e = it * 256 + tid;
        int icg = e / 108;
        int p   = e - icg * 108;
        int py = p / 18, px = p - py * 18;
        int hy = h0 + py - 1, wx = w0 + px - 1;
        bool valid = (e < 864) && ((unsigned)hy < 64u) && ((unsigned)wx < 64u);
        int off = valid ? (icg * 4096 + hy * 64 + wx) : 0;
        float a = xg[off];
        float c = xg[off + 8 * 4096];
        if (!valid) { a = 0.f; c = 0.f; } else { imgbits |= (1u << it); }
        xv1[it] = a;
        xv2[it] = c;
    }

// stage one element: spline q's via funnel-shift + cvt_pk, tanh-form gelu
#define STAGE(V, IMGF, ROWP, SLOT)                                            \
    do {                                                                      \
        float v_ = (V);                                                       \
        float tpos_ = (v_ + 2.2f) * 2.5f;                                     \
        float cf_ = floorf(tpos_);                                            \
        int ci_ = (int)cf_;                                                   \
        float u_ = tpos_ - cf_;                                               \
        float u2_ = u_ * u_, u3_ = u2_ * u_, om_ = 1.f - u_;                  \
        float q0_ = om_ * om_ * om_ * (1.f / 6.f);                            \
        float q1_ = (4.f - 6.f * u2_ + 3.f * u3_) * (1.f / 6.f);              \
        float q2_ = (1.f + 3.f * u_ + 3.f * u2_ - 3.f * u3_) * (1.f / 6.f);   \
        float q3_ = u3_ * (1.f / 6.f);                                        \
        u64 Q_ = (u64)cvtpk_bf16(q0_, q1_)                                    \
               | ((u64)cvtpk_bf16(q2_, q3_) << 32);                           \
        u64 lo_ = 0, hi_ = 0;                                                 \
        if ((IMGF) && ci_ >= 0 && ci_ <= 10) {                                \
            int s_ = ci_ * 16 - 48;                                           \
            if (s_ < 0)       { lo_ = Q_ >> (-s_); }                          \
            else if (s_ < 64) { lo_ = Q_ << s_;                               \
                                hi_ = s_ ? (Q_ >> (64 - s_)) : 0ull; }        \
            else              { hi_ = Q_ << (s_ - 64); }                      \
        }                                                                     \
        union { u64 q[2]; short8 s8; } un_;                                   \
        un_.q[0] = lo_; un_.q[1] = hi_;                                       \
        ushort* row_ = &Fs[(ROWP) * 152];                                     \
        *(short8*)(row_ + (SLOT) * 8) = un_.s8;                               \
        float x3_ = v_ * v_ * v_;                                             \
        float t2_ = fmaf(0.0713548163f, x3_, 1.5957691216f * v_);             \
        float e2_ = __expf(t2_);                                              \
        float th_ = 1.f - 2.f / (e2_ + 1.f);                                  \
        float ge_ = 0.5f * v_ * (1.f + th_);                                  \
        row_[128 + (SLOT)] = f2bf(ge_);                                       \
    } while (0)

#define STAGE_IT(IT, XV, SB)                                                  \
    do {                                                                      \
        int e_ = (IT) * 256 + tid;                                            \
        int icg_ = e_ / 108;                                                  \
        int p_ = e_ - icg_ * 108;                                             \
        int rowp_ = (e_ < 864) ? p_ : 108;   /* dump row for overflow */      \
        bool im_ = (imgbits >> (IT)) & 1u;                                    \
        STAGE((XV)[IT], im_, rowp_, icg_ + (SB));                             \
    } while (0)

    // ---- half-1 staging (icg 0-7, k 0-63 + gelu 128-135) ----
    STAGE_IT(0, xv1, 0);
    STAGE_IT(1, xv1, 0);
    STAGE_IT(2, xv1, 0);
    STAGE_IT(3, xv1, 0);
    __syncthreads();

    const int wv = tid >> 6;
    const int l  = tid & 63;
    const int la = l & 31, klo = l >> 5;
    const int p0row = la >> 4, p0col = la & 15;   // tile0: rows 0-1; tile1: +2
    const short8* w8 = (const short8*)w2;

    f32x16 accA, accB;
#pragma unroll
    for (int i = 0; i < 16; ++i) { accA[i] = 0.f; accB[i] = 0.f; }

#define TAPKS(TAP, K0, K1)                                                     \
    do {                                                                       \
        const int kh_ = (TAP) / 3, kw_ = (TAP) - kh_ * 3;                      \
        const ushort* fb0_ =                                                   \
            &Fs[((p0row + kh_) * 18 + (p0col + kw_)) * 152 + klo * 8];         \
        const ushort* fb1_ = fb0_ + 2 * 18 * 152;                              \
        const short8* ap_ = w8 + (TAP) * 576 + l;                              \
        _Pragma("unroll")                                                      \
        for (int ks_ = (K0); ks_ < (K1); ++ks_) {                              \
            short8 a_  = ap_[ks_ * 64];                                        \
            short8 b0_ = *(const short8*)(fb0_ + ks_ * 16);                    \
            short8 b1_ = *(const short8*)(fb1_ + ks_ * 16);                    \
            accA = __builtin_amdgcn_mfma_f32_32x32x16_bf16(a_, b0_, accA, 0, 0, 0); \
            accB = __builtin_amdgcn_mfma_f32_32x32x16_bf16(a_, b1_, accB, 0, 0, 0); \
        }                                                                      \
    } while (0)

    const int t0 = wv * 2, t1 = wv * 2 + 1;

    // ---- region A: half-2 staging interleaved with MFMA over half-1 K ----
    // (ks 0-3 reads only k<64 = icg0-7 slots; half-2 writes k 64-127,136-143;
    //  disjoint -> safe to interleave)
    STAGE_IT(0, xv2, 8);
    STAGE_IT(1, xv2, 8);
    TAPKS(t0, 0, 2);
    STAGE_IT(2, xv2, 8);
    TAPKS(t0, 2, 4);
    STAGE_IT(3, xv2, 8);
    TAPKS(t1, 0, 4);
    if (wv == 3) TAPKS(8, 0, 4);
    __syncthreads();

    // ---- region B: remaining K (icg 8-15 splines + all gelu) ----
    TAPKS(t0, 4, 9);
    TAPKS(t1, 4, 9);
    if (wv == 3) TAPKS(8, 4, 9);
#undef TAPKS
#undef STAGE_IT
#undef STAGE

    // ---- combine: 6 slots [slot][lane] stride 20 f32 (30,720 B in Fs) ----
    __syncthreads();                      // all feature reads done
    float* comb = (float*)Fs;
    if (wv != 0) {                        // tile0 partials: waves 1,2,3 -> 0,1,2
        float* cp = comb + ((wv - 1) * 64 + l) * 20;
        *(f32x4*)(cp + 0)  = f32x4{accA[0], accA[1], accA[2], accA[3]};
        *(f32x4*)(cp + 4)  = f32x4{accA[4], accA[5], accA[6], accA[7]};
        *(f32x4*)(cp + 8)  = f32x4{accA[8], accA[9], accA[10], accA[11]};
        *(f32x4*)(cp + 12) = f32x4{accA[12], accA[13], accA[14], accA[15]};
    }
    if (wv != 1) {                        // tile1 partials: waves 0,2,3 -> 3,4,5
        int slot = (wv == 0) ? 3 : (2 + wv);
        float* cp = comb + (slot * 64 + l) * 20;
        *(f32x4*)(cp + 0)  = f32x4{accB[0], accB[1], accB[2], accB[3]};
        *(f32x4*)(cp + 4)  = f32x4{accB[4], accB[5], accB[6], accB[7]};
        *(f32x4*)(cp + 8)  = f32x4{accB[8], accB[9], accB[10], accB[11]};
        *(f32x4*)(cp + 12) = f32x4{accB[12], accB[13], accB[14], accB[15]};
    }
    __syncthreads();
    if (wv < 2) {
        f32x16 sum = (wv == 0) ? accA : accB;
        const int sbase = (wv == 0) ? 0 : 3;
#pragma unroll
        for (int s = 0; s < 3; ++s) {
            const float* cp = comb + ((sbase + s) * 64 + l) * 20;
            f32x4 c0 = *(const f32x4*)(cp + 0);
            f32x4 c1 = *(const f32x4*)(cp + 4);
            f32x4 c2 = *(const f32x4*)(cp + 8);
            f32x4 c3 = *(const f32x4*)(cp + 12);
#pragma unroll
            for (int r = 0; r < 4; ++r) {
                sum[r]      += c0[r];
                sum[r + 4]  += c1[r];
                sum[r + 8]  += c2[r];
                sum[r + 12] += c3[r];
            }
        }
        // D: col(pixel) = lane&31, row(oc) = (r&3) + 8*(r>>2) + 4*klo
        const int pix = wv * 32 + la;
        const int prow = pix >> 4, pcol = pix & 15;
        ushort* yb = yraw + (((size_t)b * 128 + g * 32) * 64 + h0 + prow) * 64
                          + w0 + pcol;
#pragma unroll
        for (int r = 0; r < 16; ++r) {
            int oc = (r & 3) + 8 * (r >> 2) + 4 * klo;
            yb[(size_t)oc * 4096] = f2bf(sum[r]);
        }
    }
}

// ---------------------------------------------------------------------------
// Instance-norm + PReLU from bf16 raw y: one block per (b,c); each thread owns
// 16 CONTIGUOUS values; 2 b128 loads + 4 float4 stores per thread.
// ---------------------------------------------------------------------------
__global__ __launch_bounds__(256) void instnorm(const ushort* __restrict__ yraw,
                                                float* __restrict__ y,
                                                const float* __restrict__ prelu) {
    const int blk = blockIdx.x;  // b*128 + c
    const int tid = threadIdx.x;
    const short8* rp = (const short8*)(yraw + (size_t)blk * 4096);
    short8 a = rp[tid * 2], c = rp[tid * 2 + 1];
    float v[16];
#pragma unroll
    for (int j = 0; j < 8; ++j) {
        v[j]     = bf2f((ushort)a[j]);
        v[8 + j] = bf2f((ushort)c[j]);
    }
    float s = 0.f, s2 = 0.f;
#pragma unroll
    for (int j = 0; j < 16; ++j) { s += v[j]; s2 += v[j] * v[j]; }
#pragma unroll
    for (int off = 32; off > 0; off >>= 1) {
        s  += __shfl_down(s, off);
        s2 += __shfl_down(s2, off);
    }
    __shared__ float red[8];
    int wave = tid >> 6;
    if ((tid & 63) == 0) { red[wave] = s; red[4 + wave] = s2; }
    __syncthreads();
    float S  = red[0] + red[1] + red[2] + red[3];
    float S2 = red[4] + red[5] + red[6] + red[7];
    float mean = S * (1.0f / 4096.0f);
    float var  = S2 * (1.0f / 4096.0f) - mean * mean;
    float rstd = rsqrtf(var + 1e-5f);
    float slope = prelu[(blk >> 5) & 3];
    float4* op = (float4*)(y + (size_t)blk * 4096) + tid * 4;
#pragma unroll
    for (int k = 0; k < 4; ++k) {
        float4 o;
        float t;
        t = (v[k * 4 + 0] - mean) * rstd; o.x = t >= 0.f ? t : slope * t;
        t = (v[k * 4 + 1] - mean) * rstd; o.y = t >= 0.f ? t : slope * t;
        t = (v[k * 4 + 2] - mean) * rstd; o.z = t >= 0.f ? t : slope * t;
        t = (v[k * 4 + 3] - mean) * rstd; o.w = t >= 0.f ? t : slope * t;
        op[k] = o;
    }
}

extern "C" void kernel_launch(void* const* d_in, const int* in_sizes, int n_in,
                              void* d_out, int out_size, void* d_ws, size_t ws_size,
                              hipStream_t stream) {
    const float* x     = (const float*)d_in[0];
    const float* lw    = (const float*)d_in[1];
    const float* prelu = (const float*)d_in[2];
    float*  out  = (float*)d_out;
    ushort* w2   = (ushort*)d_ws;                       // 82,944 B
    ushort* yraw = (ushort*)((char*)d_ws + 92160);      // 8 MB bf16 raw y

    wtrans<<<21, 256, 0, stream>>>(lw, w2);
    dim3 grid(64, 8, 4);
    kanconv<<<grid, 256, 0, stream>>>(x, w2, yraw);
    instnorm<<<1024, 256, 0, stream>>>(yraw, out, prelu);
}